// Round 8
// baseline (33.603 us; speedup 1.0000x reference)
//
#include <hip/hip_runtime.h>

#define NV 8192
#define NF 16384
#define BATCH 32
#define VPB 64            // vertices per build block (128 blocks, 64 KiB LDS bitmap)
#define WORDS 256         // 8192 bits / 32 per row
#define MAXD 64           // list capacity; P(distinct deg > 64) ~ 1e-15 per vertex

typedef unsigned short ushort_t;

// ---------------------------------------------------------------------------
// Node 1: build.
//  (a) transpose x (packed [b][v][3] f32) -> x4 ([b][v] float4, pad) so the
//      gather can use single ds_read_b128 per neighbor. Independent global
//      work that hides under the face-scan latency.
//  (b) per-block 64 KiB LDS bit-adjacency (64 rows x 8192 bits); scan ALL
//      faces with uint4 loads; atomicOr = exact .set(-1) dedup semantics.
//  (c) fixed-trip compaction -> VALUE-SORTED row-major nbr[v][64] lists.
//  info[v] = deg | (cnt << 16); deg = popcount incl self (row-norm divisor),
//  cnt = list length excl self. Sorted lists -> deterministic gather sums.
// ---------------------------------------------------------------------------
__global__ __launch_bounds__(1024)
void build_kernel(const int* __restrict__ faces,
                  const float* __restrict__ x,
                  float4* __restrict__ x4,
                  unsigned* __restrict__ info,
                  ushort_t* __restrict__ nbr,
                  int* __restrict__ counter) {
    __shared__ unsigned bits[VPB][WORDS];   // 64 KiB

    const int t    = threadIdx.x;
    const int base = blockIdx.x * VPB;
    const int gid  = blockIdx.x * 1024 + t;   // 0..131071 (128 blocks)

    // ---- (a) transpose: 262144 vertex-slots, 2 per thread ----
    #pragma unroll
    for (int s = 0; s < 2; ++s) {
        const int slot = gid + s * 131072;          // 0..262143
        const float* src = x + (size_t)slot * 3;
        x4[slot] = make_float4(src[0], src[1], src[2], 0.f);
    }

    // ---- zero bitmap: 16384 words = 4096 uint4, 4 per thread ----
    uint4* bz = reinterpret_cast<uint4*>(&bits[0][0]);
    #pragma unroll
    for (int k = 0; k < 4; ++k) bz[t + k * 1024] = make_uint4(0, 0, 0, 0);
    if (blockIdx.x == 0 && t == 0) *counter = 0;   // for gather's last-block logic
    __syncthreads();

    // ---- (b) face scan: 4 faces = 3 uint4 per thread per iteration ----
    const uint4* f4 = reinterpret_cast<const uint4*>(faces);   // 12288 uint4
    #define SETB(vi, w) atomicOr(&bits[vi][(int)(w) >> 5], 1u << ((w) & 31))
    #define PROC(a, b, c) { \
        const unsigned ra = (unsigned)((int)(a) - base); \
        const unsigned rb = (unsigned)((int)(b) - base); \
        const unsigned rc = (unsigned)((int)(c) - base); \
        if (ra < VPB) { SETB(ra, (b)); SETB(ra, (c)); } \
        if (rb < VPB) { SETB(rb, (a)); SETB(rb, (c)); } \
        if (rc < VPB) { SETB(rc, (b)); SETB(rc, (a)); } }
    #pragma unroll
    for (int i = 0; i < NF / 4096; ++i) {          // 4 iterations
        const int j = (i * 1024 + t) * 3;
        const uint4 p = f4[j], q = f4[j + 1], r = f4[j + 2];
        PROC(p.x, p.y, p.z);
        PROC(p.w, q.x, q.y);
        PROC(q.z, q.w, r.x);
        PROC(r.y, r.z, r.w);
    }
    #undef PROC
    #undef SETB
    __syncthreads();

    // ---- (c) compact: one wave per vertex, 4 vertices per wave ----
    const int lane = t & 63;
    const int wid  = t >> 6;                       // 0..15
    #pragma unroll
    for (int s = 0; s < 4; ++s) {
        const int vi = wid * 4 + s;                // 0..63
        const int v  = base + vi;

        const uint4 wq = reinterpret_cast<const uint4*>(&bits[vi][0])[lane];
        unsigned wm[4] = {wq.x, wq.y, wq.z, wq.w};

        int pc = __popc(wm[0]) + __popc(wm[1]) + __popc(wm[2]) + __popc(wm[3]);

        // remove self-bit from the list (kept in deg)
        const int selfword = v >> 5;
        const int wbase0   = lane * 4;
        int c = pc;
        if (selfword >= wbase0 && selfword < wbase0 + 4) {
            const unsigned m = 1u << (v & 31);
            if (wm[selfword - wbase0] & m) { wm[selfword - wbase0] &= ~m; c -= 1; }
        }

        // wave-wide inclusive scan of c (list offsets) + totals
        int incl = c;
        #pragma unroll
        for (int off = 1; off < 64; off <<= 1) {
            int o = __shfl_up(incl, off);
            if (lane >= off) incl += o;
        }
        const int ofs     = incl - c;
        const int total_c = __shfl(incl, 63);

        int pct = pc;
        #pragma unroll
        for (int off = 1; off < 64; off <<= 1) pct += __shfl_xor(pct, off);

        int idx = ofs;
        #pragma unroll
        for (int jw = 0; jw < 4; ++jw) {
            unsigned bb = wm[jw];
            const int wb = (wbase0 + jw) << 5;
            while (bb) {
                const int bpos = __ffs(bb) - 1;
                bb &= bb - 1;
                if (idx < MAXD) nbr[(size_t)v * MAXD + idx] = (ushort_t)(wb + bpos);
                ++idx;
            }
        }
        if (lane == 0)
            info[v] = (unsigned)pct |
                      ((unsigned)(total_c < MAXD ? total_c : MAXD) << 16);
    }
}

// ---------------------------------------------------------------------------
// Node 2: gather + fused final reduction.
// Grid = 32 batches x 8 vertex-groups, 1024 thr/block; x4[b] (128 KiB,
// float4-padded) staged in LDS so each neighbor fetch is ONE ds_read_b128.
// Neighbor ids (k<32) loaded up-front with 4 independent uint4 loads;
// fully-unrolled predicated accumulate with wave-uniform early exit at
// kmax = wave-max(cv). Rare global tail for cv>32. Ascending sum order
// (identical adds to R7) -> bitwise deterministic.
// ---------------------------------------------------------------------------
__global__ __launch_bounds__(1024)
void gather_kernel(const float4* __restrict__ x4,
                   const unsigned* __restrict__ info,
                   const ushort_t* __restrict__ nbr,
                   float* __restrict__ partials,
                   int* __restrict__ counter,
                   float* __restrict__ out) {
    __shared__ float4 lx4[NV];       // 128 KiB
    __shared__ float red[16];
    __shared__ int isLast;

    const int t = threadIdx.x;
    const int b = blockIdx.x >> 3;
    const int g = blockIdx.x & 7;

    // stage x4[b]: 8192 float4 = 8 coalesced b128 copies per thread
    const float4* xs = x4 + (size_t)b * NV;
    #pragma unroll
    for (int i = 0; i < 8; ++i) lx4[t + i * 1024] = xs[t + i * 1024];

    const int v = g * 1024 + t;
    const unsigned iv = info[v];
    const int dv = (int)(iv & 0xFFFFu);
    const int cv = (int)(iv >> 16);

    // issue the 4 neighbor-id vector loads early (independent of LDS staging)
    const uint4* np = reinterpret_cast<const uint4*>(nbr + (size_t)v * MAXD);
    const uint4 n0 = np[0], n1 = np[1], n2 = np[2], n3 = np[3];
    const unsigned nd[16] = {n0.x, n0.y, n0.z, n0.w,
                             n1.x, n1.y, n1.z, n1.w,
                             n2.x, n2.y, n2.z, n2.w,
                             n3.x, n3.y, n3.z, n3.w};

    // wave-uniform trip bound
    int kmax = cv;
    #pragma unroll
    for (int off = 1; off < 64; off <<= 1) {
        int o = __shfl_xor(kmax, off);
        kmax = kmax > o ? kmax : o;
    }

    __syncthreads();   // staging complete

    float s0 = 0.f, s1 = 0.f, s2 = 0.f;
    #pragma unroll
    for (int k = 0; k < 32; ++k) {                 // fully unrolled: nd[] static
        if (k >= kmax) break;                      // wave-uniform early exit
        if (k < cv) {
            const int w = (int)((nd[k >> 1] >> ((k & 1) * 16)) & 0xFFFFu);
            const float4 q = lx4[w];               // one ds_read_b128
            s0 += q.x; s1 += q.y; s2 += q.z;
        }
    }
    if (kmax > 32) {                               // rare (expected ~0-1 vertices)
        for (int k = 32; k < cv; ++k) {
            const float4 q = lx4[(int)nbr[(size_t)v * MAXD + k]];
            s0 += q.x; s1 += q.y; s2 += q.z;
        }
    }

    float r = 0.f;
    if (dv > 0) {
        const float inv = 1.0f / (float)dv;
        const float4 sv = lx4[v];
        const float y0 = sv.x - s0 * inv;
        const float y1 = sv.y - s1 * inv;
        const float y2 = sv.z - s2 * inv;
        r = y0 * y0 + y1 * y1 + y2 * y2;
    }

    // deterministic block reduction over 1024 threads
    #pragma unroll
    for (int off = 32; off > 0; off >>= 1) r += __shfl_down(r, off);
    if ((t & 63) == 0) red[t >> 6] = r;
    __syncthreads();

    if (t == 0) {
        float s = 0.f;
        #pragma unroll
        for (int i = 0; i < 16; ++i) s += red[i];
        __hip_atomic_store(&partials[blockIdx.x], s,
                           __ATOMIC_RELAXED, __HIP_MEMORY_SCOPE_AGENT);
        int old = __hip_atomic_fetch_add(counter, 1,
                                         __ATOMIC_ACQ_REL, __HIP_MEMORY_SCOPE_AGENT);
        isLast = (old == (int)gridDim.x - 1);
    }
    __syncthreads();

    if (isLast && t < BATCH) {
        float s = 0.f;
        #pragma unroll
        for (int gg = 0; gg < 8; ++gg)
            s += __hip_atomic_load(&partials[t * 8 + gg],
                                   __ATOMIC_RELAXED, __HIP_MEMORY_SCOPE_AGENT);
        out[t] = s / (float)NV;
    }
}

extern "C" void kernel_launch(void* const* d_in, const int* in_sizes, int n_in,
                              void* d_out, int out_size, void* d_ws, size_t ws_size,
                              hipStream_t stream) {
    const float* x   = (const float*)d_in[0];   // (32, 8192, 3) f32
    const int* faces = (const int*)d_in[1];     // (16384, 3) i32
    float* out       = (float*)d_out;           // (32,) f32

    char* ws = (char*)d_ws;
    float4*   x4      = (float4*)ws;                            // 4 MiB: [32][8192] float4
    ushort_t* nbr     = (ushort_t*)(ws + (size_t)BATCH * NV * 16);        // 1 MiB
    unsigned* info    = (unsigned*)((char*)nbr + (size_t)MAXD * NV * 2);  // 32 KiB
    int*      counter = (int*)(info + NV);                      // 4 B (zeroed by build)
    float*    partials= (float*)(counter + 64);                 // 1 KiB

    build_kernel <<<NV / VPB, 1024, 0, stream>>>(faces, x, x4, info, nbr, counter);
    gather_kernel<<<BATCH * 8, 1024, 0, stream>>>(x4, info, nbr, partials, counter, out);
}

// Round 9
// 24.028 us; speedup vs baseline: 1.3985x; 1.3985x over previous
//
#include <hip/hip_runtime.h>

#define NV 8192
#define NF 16384
#define BATCH 32
#define VPB 32            // vertices per build block (256 blocks)
#define WORDS 256         // 8192 bits / 32 per row
#define MAXD 64           // list capacity; P(distinct deg > 64) ~ 1e-15 per vertex

typedef unsigned short ushort_t;

// ---------------------------------------------------------------------------
// Node 1: build (R6/R7 proven structure). Per-block 32 KiB LDS bit-adjacency
// (32 rows x 8192 bits); scan ALL faces with uint4 loads; atomicOr = exact
// .set(-1) dedup semantics; fixed-trip compaction emits VALUE-SORTED
// row-major nbr[v][64] lists, NOW PADDED to MAXD with sentinel id NV so the
// gather inner loop needs no per-lane predication (lx[NV] == 0.0f).
//   info[v] = deg | (cnt << 16); deg = popcount incl self (row-norm divisor),
//   cnt = list length excl self. Sorted lists -> deterministic gather sums.
// ---------------------------------------------------------------------------
__global__ __launch_bounds__(1024)
void build_kernel(const int* __restrict__ faces,
                  unsigned* __restrict__ info,
                  ushort_t* __restrict__ nbr,
                  int* __restrict__ counter) {
    __shared__ unsigned bits[VPB][WORDS];   // 32 KiB

    const int t    = threadIdx.x;
    const int base = blockIdx.x * VPB;

    // zero bitmap: 8192 words = 2048 uint4, 2 per thread
    uint4* bz = reinterpret_cast<uint4*>(&bits[0][0]);
    bz[t]        = make_uint4(0, 0, 0, 0);
    bz[t + 1024] = make_uint4(0, 0, 0, 0);
    if (blockIdx.x == 0 && t == 0) *counter = 0;   // for gather's last-block logic
    __syncthreads();

    // ---- face scan: 4 faces = 3 uint4 per thread per iteration ----
    const uint4* f4 = reinterpret_cast<const uint4*>(faces);   // 12288 uint4
    #define SETB(vi, w) atomicOr(&bits[vi][(int)(w) >> 5], 1u << ((w) & 31))
    #define PROC(a, b, c) { \
        const unsigned ra = (unsigned)((int)(a) - base); \
        const unsigned rb = (unsigned)((int)(b) - base); \
        const unsigned rc = (unsigned)((int)(c) - base); \
        if (ra < VPB) { SETB(ra, (b)); SETB(ra, (c)); } \
        if (rb < VPB) { SETB(rb, (a)); SETB(rb, (c)); } \
        if (rc < VPB) { SETB(rc, (b)); SETB(rc, (a)); } }
    #pragma unroll
    for (int i = 0; i < NF / 4096; ++i) {          // 4 iterations
        const int j = (i * 1024 + t) * 3;
        const uint4 p = f4[j], q = f4[j + 1], r = f4[j + 2];
        PROC(p.x, p.y, p.z);
        PROC(p.w, q.x, q.y);
        PROC(q.z, q.w, r.x);
        PROC(r.y, r.z, r.w);
    }
    #undef PROC
    #undef SETB
    __syncthreads();

    // ---- compact: one wave per vertex, 2 vertices per wave (fixed-trip) ----
    const int lane = t & 63;
    const int wid  = t >> 6;                       // 0..15
    #pragma unroll
    for (int s = 0; s < 2; ++s) {
        const int vi = wid * 2 + s;                // 0..31
        const int v  = base + vi;

        const uint4 wq = reinterpret_cast<const uint4*>(&bits[vi][0])[lane];
        unsigned wm[4] = {wq.x, wq.y, wq.z, wq.w};

        int pc = __popc(wm[0]) + __popc(wm[1]) + __popc(wm[2]) + __popc(wm[3]);

        // remove self-bit from the list (kept in deg)
        const int selfword = v >> 5;
        const int wbase0   = lane * 4;
        int c = pc;
        if (selfword >= wbase0 && selfword < wbase0 + 4) {
            const unsigned m = 1u << (v & 31);
            if (wm[selfword - wbase0] & m) { wm[selfword - wbase0] &= ~m; c -= 1; }
        }

        // wave-wide inclusive scan of c (list offsets) + totals
        int incl = c;
        #pragma unroll
        for (int off = 1; off < 64; off <<= 1) {
            int o = __shfl_up(incl, off);
            if (lane >= off) incl += o;
        }
        const int ofs     = incl - c;
        const int total_c = __shfl(incl, 63);

        int pct = pc;
        #pragma unroll
        for (int off = 1; off < 64; off <<= 1) pct += __shfl_xor(pct, off);

        int idx = ofs;
        #pragma unroll
        for (int jw = 0; jw < 4; ++jw) {
            unsigned bb = wm[jw];
            const int wb = (wbase0 + jw) << 5;
            while (bb) {
                const int bpos = __ffs(bb) - 1;
                bb &= bb - 1;
                if (idx < MAXD) nbr[(size_t)v * MAXD + idx] = (ushort_t)(wb + bpos);
                ++idx;
            }
        }
        // pad the rest of the row with the sentinel id NV (lx[NV] == 0)
        for (int p = total_c + lane; p < MAXD; p += 64)
            nbr[(size_t)v * MAXD + p] = (ushort_t)NV;

        if (lane == 0)
            info[v] = (unsigned)pct |
                      ((unsigned)(total_c < MAXD ? total_c : MAXD) << 16);
    }
}

// ---------------------------------------------------------------------------
// Node 2: gather + fused final reduction (R7 structure).
// Grid = 32 batches x 8 vertex-groups, 1024 thr/block; x[b] (96 KB + one
// zeroed sentinel vertex) staged in LDS. Neighbor ids (k<32) loaded up-front
// with 4 independent uint4 loads; inner loop is UNPREDICATED (sentinel pads
// add exact 0.0f) with a SCALAR (readfirstlane) wave-uniform trip bound.
// Ascending sum order, identical adds -> bitwise deterministic.
// ---------------------------------------------------------------------------
__global__ __launch_bounds__(1024)
void gather_kernel(const float* __restrict__ x,
                   const unsigned* __restrict__ info,
                   const ushort_t* __restrict__ nbr,
                   float* __restrict__ partials,
                   int* __restrict__ counter,
                   float* __restrict__ out) {
    __shared__ float lx[(NV + 1) * 3];   // 96 KiB + sentinel vertex (zeros)
    __shared__ float red[16];
    __shared__ int isLast;

    const int t = threadIdx.x;
    const int b = blockIdx.x >> 3;
    const int g = blockIdx.x & 7;

    // stage x[b]: 24576 floats = 6144 float4, coalesced
    const float4* xs = reinterpret_cast<const float4*>(x + (size_t)b * NV * 3);
    float4* ls = reinterpret_cast<float4*>(lx);
    #pragma unroll
    for (int i = 0; i < 6; ++i) ls[t + i * 1024] = xs[t + i * 1024];
    if (t == 0) { lx[NV * 3] = 0.f; lx[NV * 3 + 1] = 0.f; lx[NV * 3 + 2] = 0.f; }

    const int v = g * 1024 + t;
    const unsigned iv = info[v];
    const int dv = (int)(iv & 0xFFFFu);

    // issue the 4 neighbor-id vector loads early (independent of LDS staging)
    const uint4* np = reinterpret_cast<const uint4*>(nbr + (size_t)v * MAXD);
    const uint4 n0 = np[0], n1 = np[1], n2 = np[2], n3 = np[3];
    const unsigned nd[16] = {n0.x, n0.y, n0.z, n0.w,
                             n1.x, n1.y, n1.z, n1.w,
                             n2.x, n2.y, n2.z, n2.w,
                             n3.x, n3.y, n3.z, n3.w};

    // wave-uniform trip bound, hoisted to SGPR
    int kmax = (int)(iv >> 16);
    #pragma unroll
    for (int off = 1; off < 64; off <<= 1) {
        int o = __shfl_xor(kmax, off);
        kmax = kmax > o ? kmax : o;
    }
    const int kmaxs = __builtin_amdgcn_readfirstlane(kmax);

    __syncthreads();   // staging complete

    float s0 = 0.f, s1 = 0.f, s2 = 0.f;
    #pragma unroll
    for (int k = 0; k < 32; ++k) {                 // fully unrolled: nd[] static
        if (k >= kmaxs) break;                     // scalar branch (SGPR bound)
        const int w = (int)((nd[k >> 1] >> ((k & 1) * 16)) & 0xFFFFu) * 3;
        s0 += lx[w];                               // sentinel rows add exact 0.0f
        s1 += lx[w + 1];
        s2 += lx[w + 2];
    }
    if (kmaxs > 32) {                              // rare (P ~ 1e-7)
        for (int k = 32; k < kmaxs; ++k) {
            const int w = (int)nbr[(size_t)v * MAXD + k] * 3;
            s0 += lx[w];
            s1 += lx[w + 1];
            s2 += lx[w + 2];
        }
    }

    float r = 0.f;
    if (dv > 0) {
        const float inv = 1.0f / (float)dv;
        const float y0 = lx[v * 3]     - s0 * inv;
        const float y1 = lx[v * 3 + 1] - s1 * inv;
        const float y2 = lx[v * 3 + 2] - s2 * inv;
        r = y0 * y0 + y1 * y1 + y2 * y2;
    }

    // deterministic block reduction over 1024 threads
    #pragma unroll
    for (int off = 32; off > 0; off >>= 1) r += __shfl_down(r, off);
    if ((t & 63) == 0) red[t >> 6] = r;
    __syncthreads();

    if (t == 0) {
        float s = 0.f;
        #pragma unroll
        for (int i = 0; i < 16; ++i) s += red[i];
        __hip_atomic_store(&partials[blockIdx.x], s,
                           __ATOMIC_RELAXED, __HIP_MEMORY_SCOPE_AGENT);
        int old = __hip_atomic_fetch_add(counter, 1,
                                         __ATOMIC_ACQ_REL, __HIP_MEMORY_SCOPE_AGENT);
        isLast = (old == (int)gridDim.x - 1);
    }
    __syncthreads();

    if (isLast && t < BATCH) {
        float s = 0.f;
        #pragma unroll
        for (int gg = 0; gg < 8; ++gg)
            s += __hip_atomic_load(&partials[t * 8 + gg],
                                   __ATOMIC_RELAXED, __HIP_MEMORY_SCOPE_AGENT);
        out[t] = s / (float)NV;
    }
}

extern "C" void kernel_launch(void* const* d_in, const int* in_sizes, int n_in,
                              void* d_out, int out_size, void* d_ws, size_t ws_size,
                              hipStream_t stream) {
    const float* x   = (const float*)d_in[0];   // (32, 8192, 3) f32
    const int* faces = (const int*)d_in[1];     // (16384, 3) i32
    float* out       = (float*)d_out;           // (32,) f32

    char* ws = (char*)d_ws;
    ushort_t* nbr     = (ushort_t*)ws;                          // 1 MiB: [8192][64] ushort
    unsigned* info    = (unsigned*)(ws + (size_t)MAXD * NV * 2);// 32 KiB
    int*      counter = (int*)(info + NV);                      // 4 B (zeroed by build)
    float*    partials= (float*)(counter + 64);                 // 1 KiB

    build_kernel <<<NV / VPB, 1024, 0, stream>>>(faces, info, nbr, counter);
    gather_kernel<<<BATCH * 8, 1024, 0, stream>>>(x, info, nbr, partials, counter, out);
}